// Round 1
// baseline (1093.104 us; speedup 1.0000x reference)
//
#include <hip/hip_runtime.h>
#include <math.h>

#define NN 100000
#define EE 1600000
#define DIN0 32
#define HID 64

// ---------------- CSR build ----------------

__global__ void count_kernel(const int* __restrict__ dst, int* __restrict__ cnt, int e) {
    int i = blockIdx.x * blockDim.x + threadIdx.x;
    if (i < e) atomicAdd(&cnt[dst[i]], 1);
}

// single block, 1024 threads: exclusive scan of cnt -> rowptr, plus inv = 1/deg
__global__ void scan_kernel(const int* __restrict__ cnt, int* __restrict__ rowptr,
                            float* __restrict__ inv, int n) {
    __shared__ int sums[1024];
    int t = threadIdx.x;
    int chunk = (n + 1023) / 1024;
    int start = t * chunk;
    int end = start + chunk; if (end > n) end = n; if (start > n) start = n;
    int s = 0;
    for (int i = start; i < end; ++i) s += cnt[i];
    sums[t] = s;
    __syncthreads();
    // Hillis-Steele inclusive scan
    for (int off = 1; off < 1024; off <<= 1) {
        int v = 0;
        if (t >= off) v = sums[t - off];
        __syncthreads();
        if (t >= off) sums[t] += v;
        __syncthreads();
    }
    int prefix = (t == 0) ? 0 : sums[t - 1];
    for (int i = start; i < end; ++i) {
        rowptr[i] = prefix;
        int c = cnt[i];
        prefix += c;
        inv[i] = (c > 0) ? (1.0f / (float)c) : 0.0f;
    }
    if (t == 1023) rowptr[n] = sums[1023];
}

__global__ void fill_kernel(const int* __restrict__ src, const int* __restrict__ dst,
                            const int* __restrict__ rowptr, int* __restrict__ fill,
                            int* __restrict__ col, int e) {
    int i = blockIdx.x * blockDim.x + threadIdx.x;
    if (i < e) {
        int d = dst[i];
        int pos = atomicAdd(&fill[d], 1);
        col[rowptr[d] + pos] = src[i];
    }
}

// ---------------- fused SAGE layer ----------------
// one wave per node; lane = feature index. Gather neighbor rows (coalesced
// 64-lane row loads), mean, then y[j] = bn[j] + sum_k a[k]*Wn[k][j] + h[k]*Wr[k][j]
// via __shfl broadcast of registers. D_OUT is always 64.

template <int DIN, bool RELU>
__global__ void sage_kernel(const float* __restrict__ h,
                            const int* __restrict__ rowptr,
                            const int* __restrict__ col,
                            const float* __restrict__ inv,
                            const float* __restrict__ Wn,
                            const float* __restrict__ bn,
                            const float* __restrict__ Wr,
                            float* __restrict__ out, int n) {
    int gw = (blockIdx.x * blockDim.x + threadIdx.x) >> 6;
    int lane = threadIdx.x & 63;
    if (gw >= n) return;

    int rs = rowptr[gw];
    int re = rowptr[gw + 1];

    float a = 0.0f;
    if (lane < DIN) {
        for (int e = rs; e < re; ++e) {
            int s = col[e];  // wave-uniform -> scalar load
            a += h[(size_t)s * DIN + lane];
        }
    }
    a *= inv[gw];
    float r = (lane < DIN) ? h[(size_t)gw * DIN + lane] : 0.0f;

    float o = bn[lane];
#pragma unroll
    for (int k = 0; k < DIN; ++k) {
        float av = __shfl(a, k);
        float rv = __shfl(r, k);
        o = fmaf(av, Wn[k * HID + lane], o);
        o = fmaf(rv, Wr[k * HID + lane], o);
    }
    if (RELU) o = fmaxf(o, 0.0f);
    out[(size_t)gw * HID + lane] = o;
}

// ---------------- predictor head ----------------
// t = relu(h @ Wp1 + bp1); out = sigmoid(t @ Wp2 + bp2). One wave per node.

__global__ void predict_kernel(const float* __restrict__ h,
                               const float* __restrict__ Wp1,
                               const float* __restrict__ bp1,
                               const float* __restrict__ Wp2,
                               const float* __restrict__ bp2,
                               float* __restrict__ out, int n) {
    int gw = (blockIdx.x * blockDim.x + threadIdx.x) >> 6;
    int lane = threadIdx.x & 63;
    if (gw >= n) return;

    float hv = h[(size_t)gw * HID + lane];
    float t = bp1[lane];
#pragma unroll
    for (int k = 0; k < HID; ++k) {
        float hk = __shfl(hv, k);
        t = fmaf(hk, Wp1[k * HID + lane], t);
    }
    t = fmaxf(t, 0.0f);
    float r = t * Wp2[lane];
#pragma unroll
    for (int off = 32; off > 0; off >>= 1) r += __shfl_xor(r, off);
    if (lane == 0) out[gw] = 1.0f / (1.0f + expf(-(r + bp2[0])));
}

extern "C" void kernel_launch(void* const* d_in, const int* in_sizes, int n_in,
                              void* d_out, int out_size, void* d_ws, size_t ws_size,
                              hipStream_t stream) {
    const float* x   = (const float*)d_in[0];
    const int* eidx  = (const int*)d_in[1];
    const float* Wn0 = (const float*)d_in[2];
    const float* bn0 = (const float*)d_in[3];
    const float* Wr0 = (const float*)d_in[4];
    const float* Wn1 = (const float*)d_in[5];
    const float* bn1 = (const float*)d_in[6];
    const float* Wr1 = (const float*)d_in[7];
    const float* Wn2 = (const float*)d_in[8];
    const float* bn2 = (const float*)d_in[9];
    const float* Wr2 = (const float*)d_in[10];
    const float* Wp1 = (const float*)d_in[11];
    const float* bp1 = (const float*)d_in[12];
    const float* Wp2 = (const float*)d_in[13];
    const float* bp2 = (const float*)d_in[14];
    float* out = (float*)d_out;

    const int* src = eidx;        // edge_index[0]
    const int* dst = eidx + EE;   // edge_index[1]

    // workspace carve-up (256B aligned)
    char* w = (char*)d_ws;
    size_t off = 0;
    auto carve = [&](size_t bytes) -> void* {
        void* p = w + off;
        off = (off + bytes + 255) & ~(size_t)255;
        return p;
    };
    int*   cnt    = (int*)carve((size_t)NN * 4);
    int*   fill   = (int*)carve((size_t)NN * 4);
    int*   rowptr = (int*)carve((size_t)(NN + 1) * 4);
    float* inv    = (float*)carve((size_t)NN * 4);
    int*   col    = (int*)carve((size_t)EE * 4);
    float* h1     = (float*)carve((size_t)NN * HID * 4);
    float* h2     = (float*)carve((size_t)NN * HID * 4);
    (void)ws_size;

    hipMemsetAsync(cnt, 0, (size_t)NN * 4, stream);
    hipMemsetAsync(fill, 0, (size_t)NN * 4, stream);

    // CSR build
    count_kernel<<<(EE + 255) / 256, 256, 0, stream>>>(dst, cnt, EE);
    scan_kernel<<<1, 1024, 0, stream>>>(cnt, rowptr, inv, NN);
    fill_kernel<<<(EE + 255) / 256, 256, 0, stream>>>(src, dst, rowptr, fill, col, EE);

    // 3 SAGE layers (wave per node)
    int blocks = (NN * 64 + 255) / 256;
    sage_kernel<DIN0, true><<<blocks, 256, 0, stream>>>(x,  rowptr, col, inv, Wn0, bn0, Wr0, h1, NN);
    sage_kernel<HID,  true><<<blocks, 256, 0, stream>>>(h1, rowptr, col, inv, Wn1, bn1, Wr1, h2, NN);
    sage_kernel<HID, false><<<blocks, 256, 0, stream>>>(h2, rowptr, col, inv, Wn2, bn2, Wr2, h1, NN);

    // predictor head
    predict_kernel<<<blocks, 256, 0, stream>>>(h1, Wp1, bp1, Wp2, bp2, out, NN);
}

// Round 2
// 721.733 us; speedup vs baseline: 1.5146x; 1.5146x over previous
//
#include <hip/hip_runtime.h>
#include <math.h>

#define NN 100000
#define EE 1600000
#define DIN0 32
#define HID 64
#define SCAN_B 1024
#define SCAN_NB ((NN + SCAN_B - 1) / SCAN_B)   // 98

// ---------------- CSR build ----------------

__global__ void count_kernel(const int* __restrict__ dst, int* __restrict__ cnt, int e) {
    int i = blockIdx.x * blockDim.x + threadIdx.x;
    if (i < e) atomicAdd(&cnt[dst[i]], 1);
}

// phase A: per-block sums of cnt, plus inv = 1/deg (independent elementwise)
__global__ void block_sum_kernel(const int* __restrict__ cnt, int* __restrict__ bsum,
                                 float* __restrict__ inv, int n) {
    __shared__ int red[SCAN_B];
    int t = threadIdx.x;
    int i = blockIdx.x * SCAN_B + t;
    int c = (i < n) ? cnt[i] : 0;
    if (i < n) inv[i] = (c > 0) ? (1.0f / (float)c) : 0.0f;
    red[t] = c;
    __syncthreads();
    for (int off = SCAN_B / 2; off > 0; off >>= 1) {
        if (t < off) red[t] += red[t + off];
        __syncthreads();
    }
    if (t == 0) bsum[blockIdx.x] = red[0];
}

// phase B: single small block converts bsum to exclusive prefix; writes rowptr[n]
__global__ void scan_sums_kernel(int* __restrict__ bsum, int* __restrict__ rowptr,
                                 int nb, int n) {
    __shared__ int s[128];
    int t = threadIdx.x;
    int v = (t < nb) ? bsum[t] : 0;
    s[t] = v;
    __syncthreads();
    for (int off = 1; off < 128; off <<= 1) {
        int u = (t >= off) ? s[t - off] : 0;
        __syncthreads();
        s[t] += u;
        __syncthreads();
    }
    if (t < nb) bsum[t] = s[t] - v;      // exclusive
    if (t == 127) rowptr[n] = s[127];    // total = E
}

// phase C: per-block local scan + block offset -> rowptr
__global__ void scan_block_kernel(const int* __restrict__ cnt, const int* __restrict__ bsum,
                                  int* __restrict__ rowptr, int n) {
    __shared__ int s[SCAN_B];
    int t = threadIdx.x;
    int i = blockIdx.x * SCAN_B + t;
    int c = (i < n) ? cnt[i] : 0;
    s[t] = c;
    __syncthreads();
    for (int off = 1; off < SCAN_B; off <<= 1) {
        int u = (t >= off) ? s[t - off] : 0;
        __syncthreads();
        s[t] += u;
        __syncthreads();
    }
    if (i < n) rowptr[i] = bsum[blockIdx.x] + s[t] - c;  // exclusive
}

__global__ void fill_kernel(const int* __restrict__ src, const int* __restrict__ dst,
                            const int* __restrict__ rowptr, int* __restrict__ fill,
                            int* __restrict__ col, int e) {
    int i = blockIdx.x * blockDim.x + threadIdx.x;
    if (i < e) {
        int d = dst[i];
        int pos = atomicAdd(&fill[d], 1);
        col[rowptr[d] + pos] = src[i];
    }
}

// ---------------- fused SAGE layer ----------------
// one wave per node; lane = feature index. Gather neighbor rows (coalesced
// 64-lane row loads), mean, then y[j] = bn[j] + sum_k a[k]*Wn[k][j] + h[k]*Wr[k][j]
// via __shfl broadcast of registers.

template <int DIN, bool RELU>
__global__ void sage_kernel(const float* __restrict__ h,
                            const int* __restrict__ rowptr,
                            const int* __restrict__ col,
                            const float* __restrict__ inv,
                            const float* __restrict__ Wn,
                            const float* __restrict__ bn,
                            const float* __restrict__ Wr,
                            float* __restrict__ out, int n) {
    int gw = (blockIdx.x * blockDim.x + threadIdx.x) >> 6;
    int lane = threadIdx.x & 63;
    if (gw >= n) return;

    int rs = rowptr[gw];
    int re = rowptr[gw + 1];

    float a = 0.0f;
    if (lane < DIN) {
        int e = rs;
        for (; e + 1 < re; e += 2) {
            int s0 = col[e];
            int s1 = col[e + 1];
            float v0 = h[(size_t)s0 * DIN + lane];
            float v1 = h[(size_t)s1 * DIN + lane];
            a += v0;
            a += v1;
        }
        if (e < re) {
            int s0 = col[e];
            a += h[(size_t)s0 * DIN + lane];
        }
    }
    a *= inv[gw];
    float r = (lane < DIN) ? h[(size_t)gw * DIN + lane] : 0.0f;

    float o = bn[lane];
#pragma unroll
    for (int k = 0; k < DIN; ++k) {
        float av = __shfl(a, k);
        float rv = __shfl(r, k);
        o = fmaf(av, Wn[k * HID + lane], o);
        o = fmaf(rv, Wr[k * HID + lane], o);
    }
    if (RELU) o = fmaxf(o, 0.0f);
    out[(size_t)gw * HID + lane] = o;
}

// ---------------- predictor head ----------------

__global__ void predict_kernel(const float* __restrict__ h,
                               const float* __restrict__ Wp1,
                               const float* __restrict__ bp1,
                               const float* __restrict__ Wp2,
                               const float* __restrict__ bp2,
                               float* __restrict__ out, int n) {
    int gw = (blockIdx.x * blockDim.x + threadIdx.x) >> 6;
    int lane = threadIdx.x & 63;
    if (gw >= n) return;

    float hv = h[(size_t)gw * HID + lane];
    float t = bp1[lane];
#pragma unroll
    for (int k = 0; k < HID; ++k) {
        float hk = __shfl(hv, k);
        t = fmaf(hk, Wp1[k * HID + lane], t);
    }
    t = fmaxf(t, 0.0f);
    float r = t * Wp2[lane];
#pragma unroll
    for (int off = 32; off > 0; off >>= 1) r += __shfl_xor(r, off);
    if (lane == 0) out[gw] = 1.0f / (1.0f + expf(-(r + bp2[0])));
}

extern "C" void kernel_launch(void* const* d_in, const int* in_sizes, int n_in,
                              void* d_out, int out_size, void* d_ws, size_t ws_size,
                              hipStream_t stream) {
    const float* x   = (const float*)d_in[0];
    const int* eidx  = (const int*)d_in[1];
    const float* Wn0 = (const float*)d_in[2];
    const float* bn0 = (const float*)d_in[3];
    const float* Wr0 = (const float*)d_in[4];
    const float* Wn1 = (const float*)d_in[5];
    const float* bn1 = (const float*)d_in[6];
    const float* Wr1 = (const float*)d_in[7];
    const float* Wn2 = (const float*)d_in[8];
    const float* bn2 = (const float*)d_in[9];
    const float* Wr2 = (const float*)d_in[10];
    const float* Wp1 = (const float*)d_in[11];
    const float* bp1 = (const float*)d_in[12];
    const float* Wp2 = (const float*)d_in[13];
    const float* bp2 = (const float*)d_in[14];
    float* out = (float*)d_out;

    const int* src = eidx;        // edge_index[0]
    const int* dst = eidx + EE;   // edge_index[1]

    // workspace carve-up (256B aligned)
    char* w = (char*)d_ws;
    size_t off = 0;
    auto carve = [&](size_t bytes) -> void* {
        void* p = w + off;
        off = (off + bytes + 255) & ~(size_t)255;
        return p;
    };
    int*   cnt    = (int*)carve((size_t)NN * 4);
    int*   fill   = (int*)carve((size_t)NN * 4);
    int*   rowptr = (int*)carve((size_t)(NN + 1) * 4);
    float* inv    = (float*)carve((size_t)NN * 4);
    int*   col    = (int*)carve((size_t)EE * 4);
    int*   bsum   = (int*)carve((size_t)SCAN_NB * 4);
    float* h1     = (float*)carve((size_t)NN * HID * 4);
    float* h2     = (float*)carve((size_t)NN * HID * 4);
    (void)ws_size;

    hipMemsetAsync(cnt, 0, (size_t)NN * 4, stream);
    hipMemsetAsync(fill, 0, (size_t)NN * 4, stream);

    // CSR build (device-wide 3-phase scan)
    count_kernel<<<(EE + 255) / 256, 256, 0, stream>>>(dst, cnt, EE);
    block_sum_kernel<<<SCAN_NB, SCAN_B, 0, stream>>>(cnt, bsum, inv, NN);
    scan_sums_kernel<<<1, 128, 0, stream>>>(bsum, rowptr, SCAN_NB, NN);
    scan_block_kernel<<<SCAN_NB, SCAN_B, 0, stream>>>(cnt, bsum, rowptr, NN);
    fill_kernel<<<(EE + 255) / 256, 256, 0, stream>>>(src, dst, rowptr, fill, col, EE);

    // 3 SAGE layers (wave per node)
    int blocks = (NN * 64 + 255) / 256;
    sage_kernel<DIN0, true><<<blocks, 256, 0, stream>>>(x,  rowptr, col, inv, Wn0, bn0, Wr0, h1, NN);
    sage_kernel<HID,  true><<<blocks, 256, 0, stream>>>(h1, rowptr, col, inv, Wn1, bn1, Wr1, h2, NN);
    sage_kernel<HID, false><<<blocks, 256, 0, stream>>>(h2, rowptr, col, inv, Wn2, bn2, Wr2, h1, NN);

    // predictor head
    predict_kernel<<<blocks, 256, 0, stream>>>(h1, Wp1, bp1, Wp2, bp2, out, NN);
}

// Round 3
// 543.501 us; speedup vs baseline: 2.0112x; 1.3279x over previous
//
#include <hip/hip_runtime.h>
#include <math.h>

#define NN 100000
#define EE 1600000
#define HID 64
#define SCAN_B 1024
#define SCAN_NB ((NN + SCAN_B - 1) / SCAN_B)   // 98

// ---------------- CSR build ----------------

__global__ void count_kernel(const int* __restrict__ dst, int* __restrict__ cnt, int e) {
    int i = blockIdx.x * blockDim.x + threadIdx.x;
    if (i < e) atomicAdd(&cnt[dst[i]], 1);
}

__global__ void block_sum_kernel(const int* __restrict__ cnt, int* __restrict__ bsum,
                                 float* __restrict__ inv, int n) {
    __shared__ int red[SCAN_B];
    int t = threadIdx.x;
    int i = blockIdx.x * SCAN_B + t;
    int c = (i < n) ? cnt[i] : 0;
    if (i < n) inv[i] = (c > 0) ? (1.0f / (float)c) : 0.0f;
    red[t] = c;
    __syncthreads();
    for (int off = SCAN_B / 2; off > 0; off >>= 1) {
        if (t < off) red[t] += red[t + off];
        __syncthreads();
    }
    if (t == 0) bsum[blockIdx.x] = red[0];
}

__global__ void scan_sums_kernel(int* __restrict__ bsum, int* __restrict__ rowptr,
                                 int nb, int n) {
    __shared__ int s[128];
    int t = threadIdx.x;
    int v = (t < nb) ? bsum[t] : 0;
    s[t] = v;
    __syncthreads();
    for (int off = 1; off < 128; off <<= 1) {
        int u = (t >= off) ? s[t - off] : 0;
        __syncthreads();
        s[t] += u;
        __syncthreads();
    }
    if (t < nb) bsum[t] = s[t] - v;      // exclusive
    if (t == 127) rowptr[n] = s[127];
}

__global__ void scan_block_kernel(const int* __restrict__ cnt, const int* __restrict__ bsum,
                                  int* __restrict__ rowptr, int n) {
    __shared__ int s[SCAN_B];
    int t = threadIdx.x;
    int i = blockIdx.x * SCAN_B + t;
    int c = (i < n) ? cnt[i] : 0;
    s[t] = c;
    __syncthreads();
    for (int off = 1; off < SCAN_B; off <<= 1) {
        int u = (t >= off) ? s[t - off] : 0;
        __syncthreads();
        s[t] += u;
        __syncthreads();
    }
    if (i < n) rowptr[i] = bsum[blockIdx.x] + s[t] - c;
}

__global__ void fill_kernel(const int* __restrict__ src, const int* __restrict__ dst,
                            const int* __restrict__ rowptr, int* __restrict__ fill,
                            int* __restrict__ col, int e) {
    int i = blockIdx.x * blockDim.x + threadIdx.x;
    if (i < e) {
        int d = dst[i];
        int pos = atomicAdd(&fill[d], 1);
        col[rowptr[d] + pos] = src[i];
    }
}

// ---------------- dense transform: hn = h@Wn ; hrb = h@Wr + bn ----------------
// 4 nodes per wave, lane = output column. Node base forced wave-uniform so the
// h-row reads become scalar (SMEM) loads; weights served from L1 (exactly 32KB).
// NOTE: h and hrb may alias (in-place): each thread reads only its own 4 rows
// (all reads precede stores in program order) -> no __restrict__ on h/hrb.

template <int DIN>
__global__ void transform_kernel(const float* h,
                                 const float* __restrict__ Wn,
                                 const float* __restrict__ bn,
                                 const float* __restrict__ Wr,
                                 float* __restrict__ hn,
                                 float* hrb) {
    int lane = threadIdx.x & 63;
    int wid = (blockIdx.x * blockDim.x + threadIdx.x) >> 6;
    int m0 = __builtin_amdgcn_readfirstlane(wid << 2);
    const float* h0 = h + (size_t)m0 * DIN;

    float an0 = 0.f, an1 = 0.f, an2 = 0.f, an3 = 0.f;
    float ar0 = 0.f, ar1 = 0.f, ar2 = 0.f, ar3 = 0.f;
#pragma unroll
    for (int k = 0; k < DIN; ++k) {
        float wn = Wn[k * HID + lane];
        float wr = Wr[k * HID + lane];
        float hk0 = h0[k];
        float hk1 = h0[DIN + k];
        float hk2 = h0[2 * DIN + k];
        float hk3 = h0[3 * DIN + k];
        an0 = fmaf(hk0, wn, an0); ar0 = fmaf(hk0, wr, ar0);
        an1 = fmaf(hk1, wn, an1); ar1 = fmaf(hk1, wr, ar1);
        an2 = fmaf(hk2, wn, an2); ar2 = fmaf(hk2, wr, ar2);
        an3 = fmaf(hk3, wn, an3); ar3 = fmaf(hk3, wr, ar3);
    }
    float b = bn[lane];
    size_t o = (size_t)m0 * HID + lane;
    hn[o] = an0; hn[o + HID] = an1; hn[o + 2 * HID] = an2; hn[o + 3 * HID] = an3;
    hrb[o] = ar0 + b; hrb[o + HID] = ar1 + b;
    hrb[o + 2 * HID] = ar2 + b; hrb[o + 3 * HID] = ar3 + b;
}

// ---------------- pure gather: hio[m] = act(inv[m]*sum(hn[col]) + hio[m]) ----
// 2 nodes per wave, 4-edge unroll -> 8 independent row loads in flight.
// col/rowptr indices forced to SGPRs (SMEM pipe). In-place on hio: each wave
// reads only its own 2 rows (before writing them); neighbor data comes from hn.

template <bool RELU>
__global__ void gather_kernel(const float* __restrict__ hn,
                              const int* __restrict__ rowptr,
                              const int* __restrict__ col,
                              const float* __restrict__ inv,
                              float* hio) {
    int lane = threadIdx.x & 63;
    int wid = (blockIdx.x * blockDim.x + threadIdx.x) >> 6;
    int m0 = __builtin_amdgcn_readfirstlane(wid << 1);

    int rs0 = __builtin_amdgcn_readfirstlane(rowptr[m0]);
    int re0 = __builtin_amdgcn_readfirstlane(rowptr[m0 + 1]);
    int re1 = __builtin_amdgcn_readfirstlane(rowptr[m0 + 2]);

    float a0 = 0.f, a1 = 0.f;
    int e0 = rs0, e1 = re0;

    // both nodes advance together: 8 row loads in flight
    while (e0 + 4 <= re0 && e1 + 4 <= re1) {
        int c00 = col[e0], c01 = col[e0 + 1], c02 = col[e0 + 2], c03 = col[e0 + 3];
        int c10 = col[e1], c11 = col[e1 + 1], c12 = col[e1 + 2], c13 = col[e1 + 3];
        float v00 = hn[(size_t)c00 * HID + lane];
        float v01 = hn[(size_t)c01 * HID + lane];
        float v02 = hn[(size_t)c02 * HID + lane];
        float v03 = hn[(size_t)c03 * HID + lane];
        float v10 = hn[(size_t)c10 * HID + lane];
        float v11 = hn[(size_t)c11 * HID + lane];
        float v12 = hn[(size_t)c12 * HID + lane];
        float v13 = hn[(size_t)c13 * HID + lane];
        a0 += (v00 + v01) + (v02 + v03);
        a1 += (v10 + v11) + (v12 + v13);
        e0 += 4; e1 += 4;
    }
    while (e0 + 4 <= re0) {
        int c0 = col[e0], c1 = col[e0 + 1], c2 = col[e0 + 2], c3 = col[e0 + 3];
        a0 += (hn[(size_t)c0 * HID + lane] + hn[(size_t)c1 * HID + lane]) +
              (hn[(size_t)c2 * HID + lane] + hn[(size_t)c3 * HID + lane]);
        e0 += 4;
    }
    while (e1 + 4 <= re1) {
        int c0 = col[e1], c1 = col[e1 + 1], c2 = col[e1 + 2], c3 = col[e1 + 3];
        a1 += (hn[(size_t)c0 * HID + lane] + hn[(size_t)c1 * HID + lane]) +
              (hn[(size_t)c2 * HID + lane] + hn[(size_t)c3 * HID + lane]);
        e1 += 4;
    }
    while (e0 < re0) { a0 += hn[(size_t)col[e0] * HID + lane]; ++e0; }
    while (e1 < re1) { a1 += hn[(size_t)col[e1] * HID + lane]; ++e1; }

    size_t o = (size_t)m0 * HID + lane;
    float r0 = fmaf(a0, inv[m0], hio[o]);
    float r1 = fmaf(a1, inv[m0 + 1], hio[o + HID]);
    if (RELU) { r0 = fmaxf(r0, 0.f); r1 = fmaxf(r1, 0.f); }
    hio[o] = r0;
    hio[o + HID] = r1;
}

// ---------------- predictor ----------------
// t = relu(h@Wp1 + bp1): same structure as transform, single matrix.

__global__ void mlp1_kernel(const float* h,
                            const float* __restrict__ Wp1,
                            const float* __restrict__ bp1,
                            float* __restrict__ t) {
    int lane = threadIdx.x & 63;
    int wid = (blockIdx.x * blockDim.x + threadIdx.x) >> 6;
    int m0 = __builtin_amdgcn_readfirstlane(wid << 2);
    const float* h0 = h + (size_t)m0 * HID;

    float a0 = 0.f, a1 = 0.f, a2 = 0.f, a3 = 0.f;
#pragma unroll
    for (int k = 0; k < HID; ++k) {
        float w = Wp1[k * HID + lane];
        a0 = fmaf(h0[k], w, a0);
        a1 = fmaf(h0[HID + k], w, a1);
        a2 = fmaf(h0[2 * HID + k], w, a2);
        a3 = fmaf(h0[3 * HID + k], w, a3);
    }
    float b = bp1[lane];
    size_t o = (size_t)m0 * HID + lane;
    t[o] = fmaxf(a0 + b, 0.f);
    t[o + HID] = fmaxf(a1 + b, 0.f);
    t[o + 2 * HID] = fmaxf(a2 + b, 0.f);
    t[o + 3 * HID] = fmaxf(a3 + b, 0.f);
}

__global__ void dot_kernel(const float* __restrict__ t,
                           const float* __restrict__ Wp2,
                           const float* __restrict__ bp2,
                           float* __restrict__ out) {
    int lane = threadIdx.x & 63;
    int gw = (blockIdx.x * blockDim.x + threadIdx.x) >> 6;
    float r = t[(size_t)gw * HID + lane] * Wp2[lane];
#pragma unroll
    for (int off = 32; off > 0; off >>= 1) r += __shfl_xor(r, off);
    if (lane == 0) out[gw] = 1.0f / (1.0f + expf(-(r + bp2[0])));
}

extern "C" void kernel_launch(void* const* d_in, const int* in_sizes, int n_in,
                              void* d_out, int out_size, void* d_ws, size_t ws_size,
                              hipStream_t stream) {
    const float* x   = (const float*)d_in[0];
    const int* eidx  = (const int*)d_in[1];
    const float* Wn0 = (const float*)d_in[2];
    const float* bn0 = (const float*)d_in[3];
    const float* Wr0 = (const float*)d_in[4];
    const float* Wn1 = (const float*)d_in[5];
    const float* bn1 = (const float*)d_in[6];
    const float* Wr1 = (const float*)d_in[7];
    const float* Wn2 = (const float*)d_in[8];
    const float* bn2 = (const float*)d_in[9];
    const float* Wr2 = (const float*)d_in[10];
    const float* Wp1 = (const float*)d_in[11];
    const float* bp1 = (const float*)d_in[12];
    const float* Wp2 = (const float*)d_in[13];
    const float* bp2 = (const float*)d_in[14];
    float* out = (float*)d_out;

    const int* src = eidx;
    const int* dst = eidx + EE;

    char* w = (char*)d_ws;
    size_t off = 0;
    auto carve = [&](size_t bytes) -> void* {
        void* p = w + off;
        off = (off + bytes + 255) & ~(size_t)255;
        return p;
    };
    int*   cnt    = (int*)carve((size_t)NN * 4);
    int*   fill   = (int*)carve((size_t)NN * 4);
    int*   rowptr = (int*)carve((size_t)(NN + 1) * 4);
    float* inv    = (float*)carve((size_t)NN * 4);
    int*   col    = (int*)carve((size_t)EE * 4);
    int*   bsum   = (int*)carve((size_t)SCAN_NB * 4);
    float* A      = (float*)carve((size_t)NN * HID * 4);   // hn / t
    float* C      = (float*)carve((size_t)NN * HID * 4);   // hrb -> h (in place)
    (void)ws_size;

    hipMemsetAsync(cnt, 0, (size_t)NN * 4, stream);
    hipMemsetAsync(fill, 0, (size_t)NN * 4, stream);

    // CSR build
    count_kernel<<<(EE + 255) / 256, 256, 0, stream>>>(dst, cnt, EE);
    block_sum_kernel<<<SCAN_NB, SCAN_B, 0, stream>>>(cnt, bsum, inv, NN);
    scan_sums_kernel<<<1, 128, 0, stream>>>(bsum, rowptr, SCAN_NB, NN);
    scan_block_kernel<<<SCAN_NB, SCAN_B, 0, stream>>>(cnt, bsum, rowptr, NN);
    fill_kernel<<<(EE + 255) / 256, 256, 0, stream>>>(src, dst, rowptr, fill, col, EE);

    const int tb = NN / 16;       // 6250 blocks: 4 waves x 4 nodes
    const int gb = NN / 8;        // 12500 blocks: 4 waves x 2 nodes
    const int db = NN / 4;        // 25000 blocks: 4 waves x 1 node

    // layer 0
    transform_kernel<32><<<tb, 256, 0, stream>>>(x, Wn0, bn0, Wr0, A, C);
    gather_kernel<true><<<gb, 256, 0, stream>>>(A, rowptr, col, inv, C);
    // layer 1
    transform_kernel<64><<<tb, 256, 0, stream>>>(C, Wn1, bn1, Wr1, A, C);
    gather_kernel<true><<<gb, 256, 0, stream>>>(A, rowptr, col, inv, C);
    // layer 2
    transform_kernel<64><<<tb, 256, 0, stream>>>(C, Wn2, bn2, Wr2, A, C);
    gather_kernel<false><<<gb, 256, 0, stream>>>(A, rowptr, col, inv, C);

    // predictor
    mlp1_kernel<<<tb, 256, 0, stream>>>(C, Wp1, bp1, A);
    dot_kernel<<<db, 256, 0, stream>>>(A, Wp2, bp2, out);
}

// Round 4
// 435.887 us; speedup vs baseline: 2.5078x; 1.2469x over previous
//
#include <hip/hip_runtime.h>
#include <math.h>

#define NN 100000
#define EE 1600000
#define HID 64
#define BKT 391                 // ceil(NN/256) buckets of 256 nodes
#define CAP 5504                // LDS pair capacity per bucket (mean ~4092, 22 sigma headroom)
#define CHUNK 4096              // edges per workgroup in binning passes
#define NWG ((EE + CHUNK - 1) / CHUNK)   // 391

// ================= CSR build: bucketed counting sort =================
// All HBM writes contiguous (runs / per-bucket regions) to avoid the 16x
// write-amplification of scattered 4B stores (round-3 fill_kernel: 107MB HBM
// writes for a 6.4MB col array).

__global__ void bucket_count_kernel(const int* __restrict__ dst, int* __restrict__ bcnt) {
    __shared__ int lc[BKT];
    int t = threadIdx.x;
    for (int b = t; b < BKT; b += 256) lc[b] = 0;
    __syncthreads();
    int base = blockIdx.x * CHUNK;
#pragma unroll
    for (int j = 0; j < CHUNK / 256; ++j) {
        int i = base + j * 256 + t;
        if (i < EE) atomicAdd(&lc[dst[i] >> 8], 1);
    }
    __syncthreads();
    for (int b = t; b < BKT; b += 256)
        if (lc[b]) atomicAdd(&bcnt[b], lc[b]);
}

__global__ void bucket_scan_kernel(const int* __restrict__ bcnt, int* __restrict__ bstart,
                                   int* __restrict__ rowptr) {
    __shared__ int s[512];
    int t = threadIdx.x;
    int v = (t < BKT) ? bcnt[t] : 0;
    s[t] = v;
    __syncthreads();
    for (int off = 1; off < 512; off <<= 1) {
        int u = (t >= off) ? s[t - off] : 0;
        __syncthreads();
        s[t] += u;
        __syncthreads();
    }
    if (t < BKT) bstart[t] = s[t] - v;        // exclusive
    if (t == BKT - 1) bstart[BKT] = s[t];     // == EE
    if (t == 0) rowptr[NN] = EE;
}

// place packed (dst&255)<<24 | src into per-bucket contiguous runs
__global__ void bucket_place_kernel(const int* __restrict__ src, const int* __restrict__ dst,
                                    const int* __restrict__ bstart, int* __restrict__ bfill,
                                    unsigned* __restrict__ pairs) {
    __shared__ int lc[BKT];
    __shared__ int lbase[BKT];
    int t = threadIdx.x;
    for (int b = t; b < BKT; b += 256) lc[b] = 0;
    __syncthreads();
    int base = blockIdx.x * CHUNK;
    int myd[CHUNK / 256];
#pragma unroll
    for (int j = 0; j < CHUNK / 256; ++j) {
        int i = base + j * 256 + t;
        myd[j] = (i < EE) ? dst[i] : -1;
        if (myd[j] >= 0) atomicAdd(&lc[myd[j] >> 8], 1);
    }
    __syncthreads();
    for (int b = t; b < BKT; b += 256) {
        int c = lc[b];
        lbase[b] = c ? (atomicAdd(&bfill[b], c) + bstart[b]) : 0;
    }
    __syncthreads();
    for (int b = t; b < BKT; b += 256) lc[b] = 0;   // re-zero for rank assignment
    __syncthreads();
#pragma unroll
    for (int j = 0; j < CHUNK / 256; ++j) {
        int i = base + j * 256 + t;
        if (myd[j] >= 0) {
            int b = myd[j] >> 8;
            int r = atomicAdd(&lc[b], 1);
            pairs[lbase[b] + r] = (unsigned)src[i] | ((unsigned)(myd[j] & 255) << 24);
        }
    }
}

// per-bucket local counting sort -> col, rowptr, inv (all writes L2-local)
__global__ void bucket_build_kernel(const unsigned* __restrict__ pairs,
                                    const int* __restrict__ bstart,
                                    int* __restrict__ rowptr, float* __restrict__ inv,
                                    int* __restrict__ col) {
    __shared__ unsigned s_pk[CAP];
    __shared__ int ncnt[256];
    __shared__ int nexcl[256];
    int b = blockIdx.x;
    int t = threadIdx.x;
    int s0 = bstart[b], s1 = bstart[b + 1];
    int ce = s1 - s0;
    ncnt[t] = 0;
    for (int e = t; e < ce && e < CAP; e += 256) s_pk[e] = pairs[s0 + e];
    __syncthreads();
    for (int e = t; e < ce; e += 256) {
        unsigned pk = (e < CAP) ? s_pk[e] : pairs[s0 + e];
        atomicAdd(&ncnt[pk >> 24], 1);
    }
    __syncthreads();
    int c = ncnt[t];
    nexcl[t] = c;
    __syncthreads();
    for (int off = 1; off < 256; off <<= 1) {
        int u = (t >= off) ? nexcl[t - off] : 0;
        __syncthreads();
        nexcl[t] += u;
        __syncthreads();
    }
    int excl = nexcl[t] - c;
    int node = (b << 8) + t;
    if (node < NN) {
        rowptr[node] = s0 + excl;
        inv[node] = (c > 0) ? (1.0f / (float)c) : 0.0f;
    }
    __syncthreads();
    nexcl[t] = excl;
    ncnt[t] = 0;            // reuse as fill counters
    __syncthreads();
    for (int e = t; e < ce; e += 256) {
        unsigned pk = (e < CAP) ? s_pk[e] : pairs[s0 + e];
        int d = pk >> 24;
        int r = atomicAdd(&ncnt[d], 1);
        col[s0 + nexcl[d] + r] = (int)(pk & 0xFFFFFFu);
    }
}

// ================= dense transform: hn = h@Wn ; hrb = h@Wr + bn =================
// 4 nodes per wave, lane = output column; h-row reads wave-uniform -> scalar loads.
// h and hrb may alias in-place (reads precede stores, no __restrict__).

template <int DIN>
__global__ void transform_kernel(const float* h,
                                 const float* __restrict__ Wn,
                                 const float* __restrict__ bn,
                                 const float* __restrict__ Wr,
                                 float* __restrict__ hn,
                                 float* hrb) {
    int lane = threadIdx.x & 63;
    int wid = (blockIdx.x * blockDim.x + threadIdx.x) >> 6;
    int m0 = __builtin_amdgcn_readfirstlane(wid << 2);
    const float* h0 = h + (size_t)m0 * DIN;

    float an0 = 0.f, an1 = 0.f, an2 = 0.f, an3 = 0.f;
    float ar0 = 0.f, ar1 = 0.f, ar2 = 0.f, ar3 = 0.f;
#pragma unroll
    for (int k = 0; k < DIN; ++k) {
        float wn = Wn[k * HID + lane];
        float wr = Wr[k * HID + lane];
        float hk0 = h0[k];
        float hk1 = h0[DIN + k];
        float hk2 = h0[2 * DIN + k];
        float hk3 = h0[3 * DIN + k];
        an0 = fmaf(hk0, wn, an0); ar0 = fmaf(hk0, wr, ar0);
        an1 = fmaf(hk1, wn, an1); ar1 = fmaf(hk1, wr, ar1);
        an2 = fmaf(hk2, wn, an2); ar2 = fmaf(hk2, wr, ar2);
        an3 = fmaf(hk3, wn, an3); ar3 = fmaf(hk3, wr, ar3);
    }
    float b = bn[lane];
    size_t o = (size_t)m0 * HID + lane;
    hn[o] = an0; hn[o + HID] = an1; hn[o + 2 * HID] = an2; hn[o + 3 * HID] = an3;
    hrb[o] = ar0 + b; hrb[o + HID] = ar1 + b;
    hrb[o + 2 * HID] = ar2 + b; hrb[o + 3 * HID] = ar3 + b;
}

// ================= pure gather =================
// 2 nodes per wave, 4-edge unroll -> 8 independent row loads in flight.

template <bool RELU>
__global__ void gather_kernel(const float* __restrict__ hn,
                              const int* __restrict__ rowptr,
                              const int* __restrict__ col,
                              const float* __restrict__ inv,
                              float* hio) {
    int lane = threadIdx.x & 63;
    int wid = (blockIdx.x * blockDim.x + threadIdx.x) >> 6;
    int m0 = __builtin_amdgcn_readfirstlane(wid << 1);

    int rs0 = __builtin_amdgcn_readfirstlane(rowptr[m0]);
    int re0 = __builtin_amdgcn_readfirstlane(rowptr[m0 + 1]);
    int re1 = __builtin_amdgcn_readfirstlane(rowptr[m0 + 2]);

    float a0 = 0.f, a1 = 0.f;
    int e0 = rs0, e1 = re0;

    while (e0 + 4 <= re0 && e1 + 4 <= re1) {
        int c00 = col[e0], c01 = col[e0 + 1], c02 = col[e0 + 2], c03 = col[e0 + 3];
        int c10 = col[e1], c11 = col[e1 + 1], c12 = col[e1 + 2], c13 = col[e1 + 3];
        float v00 = hn[(size_t)c00 * HID + lane];
        float v01 = hn[(size_t)c01 * HID + lane];
        float v02 = hn[(size_t)c02 * HID + lane];
        float v03 = hn[(size_t)c03 * HID + lane];
        float v10 = hn[(size_t)c10 * HID + lane];
        float v11 = hn[(size_t)c11 * HID + lane];
        float v12 = hn[(size_t)c12 * HID + lane];
        float v13 = hn[(size_t)c13 * HID + lane];
        a0 += (v00 + v01) + (v02 + v03);
        a1 += (v10 + v11) + (v12 + v13);
        e0 += 4; e1 += 4;
    }
    while (e0 + 4 <= re0) {
        int c0 = col[e0], c1 = col[e0 + 1], c2 = col[e0 + 2], c3 = col[e0 + 3];
        a0 += (hn[(size_t)c0 * HID + lane] + hn[(size_t)c1 * HID + lane]) +
              (hn[(size_t)c2 * HID + lane] + hn[(size_t)c3 * HID + lane]);
        e0 += 4;
    }
    while (e1 + 4 <= re1) {
        int c0 = col[e1], c1 = col[e1 + 1], c2 = col[e1 + 2], c3 = col[e1 + 3];
        a1 += (hn[(size_t)c0 * HID + lane] + hn[(size_t)c1 * HID + lane]) +
              (hn[(size_t)c2 * HID + lane] + hn[(size_t)c3 * HID + lane]);
        e1 += 4;
    }
    while (e0 < re0) { a0 += hn[(size_t)col[e0] * HID + lane]; ++e0; }
    while (e1 < re1) { a1 += hn[(size_t)col[e1] * HID + lane]; ++e1; }

    size_t o = (size_t)m0 * HID + lane;
    float r0 = fmaf(a0, inv[m0], hio[o]);
    float r1 = fmaf(a1, inv[m0 + 1], hio[o + HID]);
    if (RELU) { r0 = fmaxf(r0, 0.f); r1 = fmaxf(r1, 0.f); }
    hio[o] = r0;
    hio[o + HID] = r1;
}

// ================= predictor =================

__global__ void mlp1_kernel(const float* h,
                            const float* __restrict__ Wp1,
                            const float* __restrict__ bp1,
                            float* __restrict__ t) {
    int lane = threadIdx.x & 63;
    int wid = (blockIdx.x * blockDim.x + threadIdx.x) >> 6;
    int m0 = __builtin_amdgcn_readfirstlane(wid << 2);
    const float* h0 = h + (size_t)m0 * HID;

    float a0 = 0.f, a1 = 0.f, a2 = 0.f, a3 = 0.f;
#pragma unroll
    for (int k = 0; k < HID; ++k) {
        float w = Wp1[k * HID + lane];
        a0 = fmaf(h0[k], w, a0);
        a1 = fmaf(h0[HID + k], w, a1);
        a2 = fmaf(h0[2 * HID + k], w, a2);
        a3 = fmaf(h0[3 * HID + k], w, a3);
    }
    float b = bp1[lane];
    size_t o = (size_t)m0 * HID + lane;
    t[o] = fmaxf(a0 + b, 0.f);
    t[o + HID] = fmaxf(a1 + b, 0.f);
    t[o + 2 * HID] = fmaxf(a2 + b, 0.f);
    t[o + 3 * HID] = fmaxf(a3 + b, 0.f);
}

__global__ void dot_kernel(const float* __restrict__ t,
                           const float* __restrict__ Wp2,
                           const float* __restrict__ bp2,
                           float* __restrict__ out) {
    int lane = threadIdx.x & 63;
    int gw = (blockIdx.x * blockDim.x + threadIdx.x) >> 6;
    float r = t[(size_t)gw * HID + lane] * Wp2[lane];
#pragma unroll
    for (int off = 32; off > 0; off >>= 1) r += __shfl_xor(r, off);
    if (lane == 0) out[gw] = 1.0f / (1.0f + expf(-(r + bp2[0])));
}

extern "C" void kernel_launch(void* const* d_in, const int* in_sizes, int n_in,
                              void* d_out, int out_size, void* d_ws, size_t ws_size,
                              hipStream_t stream) {
    const float* x   = (const float*)d_in[0];
    const int* eidx  = (const int*)d_in[1];
    const float* Wn0 = (const float*)d_in[2];
    const float* bn0 = (const float*)d_in[3];
    const float* Wr0 = (const float*)d_in[4];
    const float* Wn1 = (const float*)d_in[5];
    const float* bn1 = (const float*)d_in[6];
    const float* Wr1 = (const float*)d_in[7];
    const float* Wn2 = (const float*)d_in[8];
    const float* bn2 = (const float*)d_in[9];
    const float* Wr2 = (const float*)d_in[10];
    const float* Wp1 = (const float*)d_in[11];
    const float* bp1 = (const float*)d_in[12];
    const float* Wp2 = (const float*)d_in[13];
    const float* bp2 = (const float*)d_in[14];
    float* out = (float*)d_out;

    const int* src = eidx;
    const int* dst = eidx + EE;

    char* w = (char*)d_ws;
    size_t off = 0;
    auto carve = [&](size_t bytes) -> void* {
        void* p = w + off;
        off = (off + bytes + 255) & ~(size_t)255;
        return p;
    };
    int*   rowptr = (int*)carve((size_t)(NN + 1) * 4);
    float* inv    = (float*)carve((size_t)NN * 4);
    int*   col    = (int*)carve((size_t)EE * 4);
    int*   bcnt   = (int*)carve((size_t)BKT * 4);
    int*   bstart = (int*)carve((size_t)(BKT + 1) * 4);
    int*   bfill  = (int*)carve((size_t)BKT * 4);
    float* A      = (float*)carve((size_t)NN * HID * 4);   // hn / t; pairs aliases this
    float* C      = (float*)carve((size_t)NN * HID * 4);   // hrb -> h (in place)
    unsigned* pairs = (unsigned*)A;   // lifetime: CSR build only, before A's first use
    (void)ws_size;

    hipMemsetAsync(bcnt, 0, (size_t)BKT * 4, stream);
    hipMemsetAsync(bfill, 0, (size_t)BKT * 4, stream);

    // CSR build: bucketed counting sort (contiguous writes only)
    bucket_count_kernel<<<NWG, 256, 0, stream>>>(dst, bcnt);
    bucket_scan_kernel<<<1, 512, 0, stream>>>(bcnt, bstart, rowptr);
    bucket_place_kernel<<<NWG, 256, 0, stream>>>(src, dst, bstart, bfill, pairs);
    bucket_build_kernel<<<BKT, 256, 0, stream>>>(pairs, bstart, rowptr, inv, col);

    const int tb = NN / 16;       // 6250 blocks: 4 waves x 4 nodes
    const int gb = NN / 8;        // 12500 blocks: 4 waves x 2 nodes
    const int db = NN / 4;        // 25000 blocks: 4 waves x 1 node

    // layer 0
    transform_kernel<32><<<tb, 256, 0, stream>>>(x, Wn0, bn0, Wr0, A, C);
    gather_kernel<true><<<gb, 256, 0, stream>>>(A, rowptr, col, inv, C);
    // layer 1
    transform_kernel<64><<<tb, 256, 0, stream>>>(C, Wn1, bn1, Wr1, A, C);
    gather_kernel<true><<<gb, 256, 0, stream>>>(A, rowptr, col, inv, C);
    // layer 2
    transform_kernel<64><<<tb, 256, 0, stream>>>(C, Wn2, bn2, Wr2, A, C);
    gather_kernel<false><<<gb, 256, 0, stream>>>(A, rowptr, col, inv, C);

    // predictor
    mlp1_kernel<<<tb, 256, 0, stream>>>(C, Wp1, bp1, A);
    dot_kernel<<<db, 256, 0, stream>>>(A, Wp2, bp2, out);
}

// Round 5
// 364.052 us; speedup vs baseline: 3.0026x; 1.1973x over previous
//
#include <hip/hip_runtime.h>
#include <math.h>

#define NN 100000
#define EE 1600000
#define HID 64
#define BKT 391                 // ceil(NN/256) buckets of 256 nodes
#define CAP 5504                // LDS pair capacity per bucket
#define CHUNK 4096              // edges per workgroup in binning passes
#define NWG ((EE + CHUNK - 1) / CHUNK)   // 391

typedef _Float16 f16;

// ================= CSR build: bucketed counting sort =================

__global__ void bucket_count_kernel(const int* __restrict__ dst, int* __restrict__ bcnt) {
    __shared__ int lc[BKT];
    int t = threadIdx.x;
    for (int b = t; b < BKT; b += 256) lc[b] = 0;
    __syncthreads();
    int base = blockIdx.x * CHUNK;
#pragma unroll
    for (int j = 0; j < CHUNK / 256; ++j) {
        int i = base + j * 256 + t;
        if (i < EE) atomicAdd(&lc[dst[i] >> 8], 1);
    }
    __syncthreads();
    for (int b = t; b < BKT; b += 256)
        if (lc[b]) atomicAdd(&bcnt[b], lc[b]);
}

__global__ void bucket_scan_kernel(const int* __restrict__ bcnt, int* __restrict__ bstart,
                                   int* __restrict__ rowptr) {
    __shared__ int s[512];
    int t = threadIdx.x;
    int v = (t < BKT) ? bcnt[t] : 0;
    s[t] = v;
    __syncthreads();
    for (int off = 1; off < 512; off <<= 1) {
        int u = (t >= off) ? s[t - off] : 0;
        __syncthreads();
        s[t] += u;
        __syncthreads();
    }
    if (t < BKT) bstart[t] = s[t] - v;        // exclusive
    if (t == BKT - 1) bstart[BKT] = s[t];     // == EE
    if (t == 0) rowptr[NN] = EE;
}

__global__ void bucket_place_kernel(const int* __restrict__ src, const int* __restrict__ dst,
                                    const int* __restrict__ bstart, int* __restrict__ bfill,
                                    unsigned* __restrict__ pairs) {
    __shared__ int lc[BKT];
    __shared__ int lbase[BKT];
    int t = threadIdx.x;
    for (int b = t; b < BKT; b += 256) lc[b] = 0;
    __syncthreads();
    int base = blockIdx.x * CHUNK;
    int myd[CHUNK / 256];
#pragma unroll
    for (int j = 0; j < CHUNK / 256; ++j) {
        int i = base + j * 256 + t;
        myd[j] = (i < EE) ? dst[i] : -1;
        if (myd[j] >= 0) atomicAdd(&lc[myd[j] >> 8], 1);
    }
    __syncthreads();
    for (int b = t; b < BKT; b += 256) {
        int c = lc[b];
        lbase[b] = c ? (atomicAdd(&bfill[b], c) + bstart[b]) : 0;
    }
    __syncthreads();
    for (int b = t; b < BKT; b += 256) lc[b] = 0;
    __syncthreads();
#pragma unroll
    for (int j = 0; j < CHUNK / 256; ++j) {
        int i = base + j * 256 + t;
        if (myd[j] >= 0) {
            int b = myd[j] >> 8;
            int r = atomicAdd(&lc[b], 1);
            pairs[lbase[b] + r] = (unsigned)src[i] | ((unsigned)(myd[j] & 255) << 24);
        }
    }
}

__global__ void bucket_build_kernel(const unsigned* __restrict__ pairs,
                                    const int* __restrict__ bstart,
                                    int* __restrict__ rowptr, float* __restrict__ inv,
                                    int* __restrict__ col) {
    __shared__ unsigned s_pk[CAP];
    __shared__ int ncnt[256];
    __shared__ int nexcl[256];
    int b = blockIdx.x;
    int t = threadIdx.x;
    int s0 = bstart[b], s1 = bstart[b + 1];
    int ce = s1 - s0;
    ncnt[t] = 0;
    for (int e = t; e < ce && e < CAP; e += 256) s_pk[e] = pairs[s0 + e];
    __syncthreads();
    for (int e = t; e < ce; e += 256) {
        unsigned pk = (e < CAP) ? s_pk[e] : pairs[s0 + e];
        atomicAdd(&ncnt[pk >> 24], 1);
    }
    __syncthreads();
    int c = ncnt[t];
    nexcl[t] = c;
    __syncthreads();
    for (int off = 1; off < 256; off <<= 1) {
        int u = (t >= off) ? nexcl[t - off] : 0;
        __syncthreads();
        nexcl[t] += u;
        __syncthreads();
    }
    int excl = nexcl[t] - c;
    int node = (b << 8) + t;
    if (node < NN) {
        rowptr[node] = s0 + excl;
        inv[node] = (c > 0) ? (1.0f / (float)c) : 0.0f;
    }
    __syncthreads();
    nexcl[t] = excl;
    ncnt[t] = 0;
    __syncthreads();
    for (int e = t; e < ce; e += 256) {
        unsigned pk = (e < CAP) ? s_pk[e] : pairs[s0 + e];
        int d = pk >> 24;
        int r = atomicAdd(&ncnt[d], 1);
        col[s0 + nexcl[d] + r] = (int)(pk & 0xFFFFFFu);
    }
}

// ================= dense transform: hn = fp16(h@Wn) ; hrb = h@Wr + bn =========
// 4 nodes per wave, lane = output column; h-row reads wave-uniform -> scalar loads.
// hn stored fp16 (gather operand, halves gather traffic); hrb fp32.
// h and hrb may alias in-place (reads precede stores, no __restrict__ on them).

template <int DIN>
__global__ void transform_kernel(const float* h,
                                 const float* __restrict__ Wn,
                                 const float* __restrict__ bn,
                                 const float* __restrict__ Wr,
                                 f16* __restrict__ hn,
                                 float* hrb) {
    int lane = threadIdx.x & 63;
    int wid = (blockIdx.x * blockDim.x + threadIdx.x) >> 6;
    int m0 = __builtin_amdgcn_readfirstlane(wid << 2);
    const float* h0 = h + (size_t)m0 * DIN;

    float an0 = 0.f, an1 = 0.f, an2 = 0.f, an3 = 0.f;
    float ar0 = 0.f, ar1 = 0.f, ar2 = 0.f, ar3 = 0.f;
#pragma unroll
    for (int k = 0; k < DIN; ++k) {
        float wn = Wn[k * HID + lane];
        float wr = Wr[k * HID + lane];
        float hk0 = h0[k];
        float hk1 = h0[DIN + k];
        float hk2 = h0[2 * DIN + k];
        float hk3 = h0[3 * DIN + k];
        an0 = fmaf(hk0, wn, an0); ar0 = fmaf(hk0, wr, ar0);
        an1 = fmaf(hk1, wn, an1); ar1 = fmaf(hk1, wr, ar1);
        an2 = fmaf(hk2, wn, an2); ar2 = fmaf(hk2, wr, ar2);
        an3 = fmaf(hk3, wn, an3); ar3 = fmaf(hk3, wr, ar3);
    }
    float b = bn[lane];
    size_t o = (size_t)m0 * HID + lane;
    hn[o] = (f16)an0; hn[o + HID] = (f16)an1;
    hn[o + 2 * HID] = (f16)an2; hn[o + 3 * HID] = (f16)an3;
    hrb[o] = ar0 + b; hrb[o + HID] = ar1 + b;
    hrb[o + 2 * HID] = ar2 + b; hrb[o + 3 * HID] = ar3 + b;
}

// ================= pure gather (fp16 rows, fp32 accumulate) =================
// 2 nodes per wave, 4-edge unroll -> 8 independent row loads in flight.

template <bool RELU>
__global__ void gather_kernel(const f16* __restrict__ hn,
                              const int* __restrict__ rowptr,
                              const int* __restrict__ col,
                              const float* __restrict__ inv,
                              float* hio) {
    int lane = threadIdx.x & 63;
    int wid = (blockIdx.x * blockDim.x + threadIdx.x) >> 6;
    int m0 = __builtin_amdgcn_readfirstlane(wid << 1);

    int rs0 = __builtin_amdgcn_readfirstlane(rowptr[m0]);
    int re0 = __builtin_amdgcn_readfirstlane(rowptr[m0 + 1]);
    int re1 = __builtin_amdgcn_readfirstlane(rowptr[m0 + 2]);

    float a0 = 0.f, a1 = 0.f;
    int e0 = rs0, e1 = re0;

    while (e0 + 4 <= re0 && e1 + 4 <= re1) {
        int c00 = col[e0], c01 = col[e0 + 1], c02 = col[e0 + 2], c03 = col[e0 + 3];
        int c10 = col[e1], c11 = col[e1 + 1], c12 = col[e1 + 2], c13 = col[e1 + 3];
        float v00 = (float)hn[(size_t)c00 * HID + lane];
        float v01 = (float)hn[(size_t)c01 * HID + lane];
        float v02 = (float)hn[(size_t)c02 * HID + lane];
        float v03 = (float)hn[(size_t)c03 * HID + lane];
        float v10 = (float)hn[(size_t)c10 * HID + lane];
        float v11 = (float)hn[(size_t)c11 * HID + lane];
        float v12 = (float)hn[(size_t)c12 * HID + lane];
        float v13 = (float)hn[(size_t)c13 * HID + lane];
        a0 += (v00 + v01) + (v02 + v03);
        a1 += (v10 + v11) + (v12 + v13);
        e0 += 4; e1 += 4;
    }
    while (e0 + 4 <= re0) {
        int c0 = col[e0], c1 = col[e0 + 1], c2 = col[e0 + 2], c3 = col[e0 + 3];
        a0 += ((float)hn[(size_t)c0 * HID + lane] + (float)hn[(size_t)c1 * HID + lane]) +
              ((float)hn[(size_t)c2 * HID + lane] + (float)hn[(size_t)c3 * HID + lane]);
        e0 += 4;
    }
    while (e1 + 4 <= re1) {
        int c0 = col[e1], c1 = col[e1 + 1], c2 = col[e1 + 2], c3 = col[e1 + 3];
        a1 += ((float)hn[(size_t)c0 * HID + lane] + (float)hn[(size_t)c1 * HID + lane]) +
              ((float)hn[(size_t)c2 * HID + lane] + (float)hn[(size_t)c3 * HID + lane]);
        e1 += 4;
    }
    while (e0 < re0) { a0 += (float)hn[(size_t)col[e0] * HID + lane]; ++e0; }
    while (e1 < re1) { a1 += (float)hn[(size_t)col[e1] * HID + lane]; ++e1; }

    size_t o = (size_t)m0 * HID + lane;
    float r0 = fmaf(a0, inv[m0], hio[o]);
    float r1 = fmaf(a1, inv[m0 + 1], hio[o + HID]);
    if (RELU) { r0 = fmaxf(r0, 0.f); r1 = fmaxf(r1, 0.f); }
    hio[o] = r0;
    hio[o + HID] = r1;
}

// ================= fused predictor head =================
// out = sigmoid(relu(h@Wp1+bp1)@Wp2 + bp2); t stays in registers.

__global__ void head_kernel(const float* __restrict__ h,
                            const float* __restrict__ Wp1,
                            const float* __restrict__ bp1,
                            const float* __restrict__ Wp2,
                            const float* __restrict__ bp2,
                            float* __restrict__ out) {
    int lane = threadIdx.x & 63;
    int wid = (blockIdx.x * blockDim.x + threadIdx.x) >> 6;
    int m0 = __builtin_amdgcn_readfirstlane(wid << 2);
    const float* h0 = h + (size_t)m0 * HID;

    float a0 = 0.f, a1 = 0.f, a2 = 0.f, a3 = 0.f;
#pragma unroll
    for (int k = 0; k < HID; ++k) {
        float w = Wp1[k * HID + lane];
        a0 = fmaf(h0[k], w, a0);
        a1 = fmaf(h0[HID + k], w, a1);
        a2 = fmaf(h0[2 * HID + k], w, a2);
        a3 = fmaf(h0[3 * HID + k], w, a3);
    }
    float b = bp1[lane], w2 = Wp2[lane];
    float r0 = fmaxf(a0 + b, 0.f) * w2;
    float r1 = fmaxf(a1 + b, 0.f) * w2;
    float r2 = fmaxf(a2 + b, 0.f) * w2;
    float r3 = fmaxf(a3 + b, 0.f) * w2;
#pragma unroll
    for (int off = 32; off > 0; off >>= 1) {
        r0 += __shfl_xor(r0, off);
        r1 += __shfl_xor(r1, off);
        r2 += __shfl_xor(r2, off);
        r3 += __shfl_xor(r3, off);
    }
    if (lane == 0) {
        float bb = bp2[0];
        out[m0]     = 1.f / (1.f + expf(-(r0 + bb)));
        out[m0 + 1] = 1.f / (1.f + expf(-(r1 + bb)));
        out[m0 + 2] = 1.f / (1.f + expf(-(r2 + bb)));
        out[m0 + 3] = 1.f / (1.f + expf(-(r3 + bb)));
    }
}

extern "C" void kernel_launch(void* const* d_in, const int* in_sizes, int n_in,
                              void* d_out, int out_size, void* d_ws, size_t ws_size,
                              hipStream_t stream) {
    const float* x   = (const float*)d_in[0];
    const int* eidx  = (const int*)d_in[1];
    const float* Wn0 = (const float*)d_in[2];
    const float* bn0 = (const float*)d_in[3];
    const float* Wr0 = (const float*)d_in[4];
    const float* Wn1 = (const float*)d_in[5];
    const float* bn1 = (const float*)d_in[6];
    const float* Wr1 = (const float*)d_in[7];
    const float* Wn2 = (const float*)d_in[8];
    const float* bn2 = (const float*)d_in[9];
    const float* Wr2 = (const float*)d_in[10];
    const float* Wp1 = (const float*)d_in[11];
    const float* bp1 = (const float*)d_in[12];
    const float* Wp2 = (const float*)d_in[13];
    const float* bp2 = (const float*)d_in[14];
    float* out = (float*)d_out;

    const int* src = eidx;
    const int* dst = eidx + EE;

    char* w = (char*)d_ws;
    size_t off = 0;
    auto carve = [&](size_t bytes) -> void* {
        void* p = w + off;
        off = (off + bytes + 255) & ~(size_t)255;
        return p;
    };
    int*   rowptr = (int*)carve((size_t)(NN + 1) * 4);
    float* inv    = (float*)carve((size_t)NN * 4);
    int*   col    = (int*)carve((size_t)EE * 4);
    int*   bcnt   = (int*)carve((size_t)BKT * 4);
    int*   bstart = (int*)carve((size_t)(BKT + 1) * 4);
    int*   bfill  = (int*)carve((size_t)BKT * 4);
    f16*   A      = (f16*)carve((size_t)NN * HID * 4);   // hn (fp16); pairs aliases this
    float* C      = (float*)carve((size_t)NN * HID * 4); // hrb -> h (in place)
    unsigned* pairs = (unsigned*)A;   // lifetime: CSR build only, before A's first use
    (void)ws_size;

    hipMemsetAsync(bcnt, 0, (size_t)BKT * 4, stream);
    hipMemsetAsync(bfill, 0, (size_t)BKT * 4, stream);

    // CSR build: bucketed counting sort (contiguous writes only)
    bucket_count_kernel<<<NWG, 256, 0, stream>>>(dst, bcnt);
    bucket_scan_kernel<<<1, 512, 0, stream>>>(bcnt, bstart, rowptr);
    bucket_place_kernel<<<NWG, 256, 0, stream>>>(src, dst, bstart, bfill, pairs);
    bucket_build_kernel<<<BKT, 256, 0, stream>>>(pairs, bstart, rowptr, inv, col);

    const int tb = NN / 16;       // 6250 blocks: 4 waves x 4 nodes
    const int gb = NN / 8;        // 12500 blocks: 4 waves x 2 nodes

    // layer 0
    transform_kernel<32><<<tb, 256, 0, stream>>>(x, Wn0, bn0, Wr0, A, C);
    gather_kernel<true><<<gb, 256, 0, stream>>>(A, rowptr, col, inv, C);
    // layer 1
    transform_kernel<64><<<tb, 256, 0, stream>>>(C, Wn1, bn1, Wr1, A, C);
    gather_kernel<true><<<gb, 256, 0, stream>>>(A, rowptr, col, inv, C);
    // layer 2
    transform_kernel<64><<<tb, 256, 0, stream>>>(C, Wn2, bn2, Wr2, A, C);
    gather_kernel<false><<<gb, 256, 0, stream>>>(A, rowptr, col, inv, C);

    // fused predictor head
    head_kernel<<<tb, 256, 0, stream>>>(C, Wp1, bp1, Wp2, bp2, out);
}

// Round 6
// 349.176 us; speedup vs baseline: 3.1305x; 1.0426x over previous
//
#include <hip/hip_runtime.h>
#include <math.h>

#define NN 100000
#define EE 1600000
#define HID 64
#define BKT 391                 // ceil(NN/256) buckets of 256 nodes
#define SLAB 5504               // slab capacity per bucket (mean ~4092, 22 sigma headroom)
#define CHUNK 4096              // edges per workgroup in placement pass
#define NWG ((EE + CHUNK - 1) / CHUNK)   // 391

typedef _Float16 f16;
typedef _Float16 f16x2 __attribute__((ext_vector_type(2)));

__device__ __forceinline__ f16x2 u2h(unsigned u) { return __builtin_bit_cast(f16x2, u); }

// ================= CSR build: slabbed bucket sort (2 kernels) =================
// Each bucket owns pairs[b*SLAB ..] and col[b*SLAB ..]; placement reserves
// contiguous runs via one global atomic per (WG,bucket); no pre-scan needed.

__global__ void place_kernel(const int* __restrict__ src, const int* __restrict__ dst,
                             int* __restrict__ bfill, unsigned* __restrict__ pairs) {
    __shared__ int lc[BKT];
    __shared__ int lbase[BKT];
    int t = threadIdx.x;
    for (int b = t; b < BKT; b += 256) lc[b] = 0;
    __syncthreads();
    int base = blockIdx.x * CHUNK;
    int myd[CHUNK / 256];
#pragma unroll
    for (int j = 0; j < CHUNK / 256; ++j) {
        int i = base + j * 256 + t;
        myd[j] = (i < EE) ? dst[i] : -1;
        if (myd[j] >= 0) atomicAdd(&lc[myd[j] >> 8], 1);
    }
    __syncthreads();
    for (int b = t; b < BKT; b += 256) {
        int c = lc[b];
        if (c) {
            int ofs = atomicAdd(&bfill[b], c);
            if (ofs + c > SLAB) ofs = SLAB - c;   // paranoia clamp (statistically unreachable)
            lbase[b] = b * SLAB + ofs;
        }
    }
    __syncthreads();
    for (int b = t; b < BKT; b += 256) lc[b] = 0;   // re-zero for rank assignment
    __syncthreads();
#pragma unroll
    for (int j = 0; j < CHUNK / 256; ++j) {
        int i = base + j * 256 + t;
        if (myd[j] >= 0) {
            int b = myd[j] >> 8;
            int r = atomicAdd(&lc[b], 1);
            pairs[lbase[b] + r] = (unsigned)src[i] | ((unsigned)(myd[j] & 255) << 24);
        }
    }
}

// per-bucket counting sort -> col (slab layout), rs/re, inv
__global__ void build_kernel(const unsigned* __restrict__ pairs,
                             const int* __restrict__ bfill,
                             int* __restrict__ rs, int* __restrict__ re,
                             float* __restrict__ inv, int* __restrict__ col) {
    __shared__ unsigned s_pk[SLAB];
    __shared__ int ncnt[256];
    __shared__ int nexcl[256];
    int b = blockIdx.x;
    int t = threadIdx.x;
    int s0 = b * SLAB;
    int ce = bfill[b]; if (ce > SLAB) ce = SLAB;
    ncnt[t] = 0;
    for (int e = t; e < ce; e += 256) s_pk[e] = pairs[s0 + e];
    __syncthreads();
    for (int e = t; e < ce; e += 256) atomicAdd(&ncnt[s_pk[e] >> 24], 1);
    __syncthreads();
    int c = ncnt[t];
    nexcl[t] = c;
    __syncthreads();
    for (int off = 1; off < 256; off <<= 1) {
        int u = (t >= off) ? nexcl[t - off] : 0;
        __syncthreads();
        nexcl[t] += u;
        __syncthreads();
    }
    int excl = nexcl[t] - c;
    int node = (b << 8) + t;
    if (node < NN) {
        rs[node] = s0 + excl;
        re[node] = s0 + excl + c;
        inv[node] = (c > 0) ? (1.0f / (float)c) : 0.0f;
    }
    __syncthreads();
    nexcl[t] = excl;
    ncnt[t] = 0;            // reuse as fill counters
    __syncthreads();
    for (int e = t; e < ce; e += 256) {
        unsigned pk = s_pk[e];
        int d = pk >> 24;
        int r = atomicAdd(&ncnt[d], 1);
        col[s0 + nexcl[d] + r] = (int)(pk & 0xFFFFFFu);
    }
}

// ================= dense transforms =================
// 4 nodes/wave, lane = output column; h-row reads wave-uniform -> scalar loads.
// All math fp32; hn and hrb stored fp16. h/hrb may alias in-place.

// layer 0: fp32 input, DIN=32
__global__ void transform32_kernel(const float* __restrict__ h,
                                   const float* __restrict__ Wn,
                                   const float* __restrict__ bn,
                                   const float* __restrict__ Wr,
                                   f16* __restrict__ hn,
                                   f16* __restrict__ hrb) {
    int lane = threadIdx.x & 63;
    int wid = (blockIdx.x * blockDim.x + threadIdx.x) >> 6;
    int m0 = __builtin_amdgcn_readfirstlane(wid << 2);
    const float* h0 = h + (size_t)m0 * 32;

    float an0 = 0.f, an1 = 0.f, an2 = 0.f, an3 = 0.f;
    float ar0 = 0.f, ar1 = 0.f, ar2 = 0.f, ar3 = 0.f;
#pragma unroll
    for (int k = 0; k < 32; ++k) {
        float wn = Wn[k * HID + lane];
        float wr = Wr[k * HID + lane];
        float hk0 = h0[k];
        float hk1 = h0[32 + k];
        float hk2 = h0[64 + k];
        float hk3 = h0[96 + k];
        an0 = fmaf(hk0, wn, an0); ar0 = fmaf(hk0, wr, ar0);
        an1 = fmaf(hk1, wn, an1); ar1 = fmaf(hk1, wr, ar1);
        an2 = fmaf(hk2, wn, an2); ar2 = fmaf(hk2, wr, ar2);
        an3 = fmaf(hk3, wn, an3); ar3 = fmaf(hk3, wr, ar3);
    }
    float b = bn[lane];
    size_t o = (size_t)m0 * HID + lane;
    hn[o] = (f16)an0; hn[o + HID] = (f16)an1;
    hn[o + 2 * HID] = (f16)an2; hn[o + 3 * HID] = (f16)an3;
    hrb[o] = (f16)(ar0 + b); hrb[o + HID] = (f16)(ar1 + b);
    hrb[o + 2 * HID] = (f16)(ar2 + b); hrb[o + 3 * HID] = (f16)(ar3 + b);
}

// layers 1/2: fp16 input, DIN=64 (packed scalar reads, 2 k's per dword)
__global__ void transform64_kernel(const f16* h,
                                   const float* __restrict__ Wn,
                                   const float* __restrict__ bn,
                                   const float* __restrict__ Wr,
                                   f16* __restrict__ hn,
                                   f16* hrb) {
    int lane = threadIdx.x & 63;
    int wid = (blockIdx.x * blockDim.x + threadIdx.x) >> 6;
    int m0 = __builtin_amdgcn_readfirstlane(wid << 2);
    const unsigned* h0 = (const unsigned*)h + (size_t)m0 * 32;   // 32 dwords/row

    float an0 = 0.f, an1 = 0.f, an2 = 0.f, an3 = 0.f;
    float ar0 = 0.f, ar1 = 0.f, ar2 = 0.f, ar3 = 0.f;
#pragma unroll
    for (int kk = 0; kk < 32; ++kk) {
        f16x2 p0 = u2h(h0[kk]);
        f16x2 p1 = u2h(h0[32 + kk]);
        f16x2 p2 = u2h(h0[64 + kk]);
        f16x2 p3 = u2h(h0[96 + kk]);
        int k = kk << 1;
        float wnA = Wn[k * HID + lane], wrA = Wr[k * HID + lane];
        float wnB = Wn[(k + 1) * HID + lane], wrB = Wr[(k + 1) * HID + lane];
        an0 = fmaf((float)p0.x, wnA, an0); an0 = fmaf((float)p0.y, wnB, an0);
        ar0 = fmaf((float)p0.x, wrA, ar0); ar0 = fmaf((float)p0.y, wrB, ar0);
        an1 = fmaf((float)p1.x, wnA, an1); an1 = fmaf((float)p1.y, wnB, an1);
        ar1 = fmaf((float)p1.x, wrA, ar1); ar1 = fmaf((float)p1.y, wrB, ar1);
        an2 = fmaf((float)p2.x, wnA, an2); an2 = fmaf((float)p2.y, wnB, an2);
        ar2 = fmaf((float)p2.x, wrA, ar2); ar2 = fmaf((float)p2.y, wrB, ar2);
        an3 = fmaf((float)p3.x, wnA, an3); an3 = fmaf((float)p3.y, wnB, an3);
        ar3 = fmaf((float)p3.x, wrA, ar3); ar3 = fmaf((float)p3.y, wrB, ar3);
    }
    float b = bn[lane];
    size_t o = (size_t)m0 * HID + lane;
    hn[o] = (f16)an0; hn[o + HID] = (f16)an1;
    hn[o + 2 * HID] = (f16)an2; hn[o + 3 * HID] = (f16)an3;
    hrb[o] = (f16)(ar0 + b); hrb[o + HID] = (f16)(ar1 + b);
    hrb[o + 2 * HID] = (f16)(ar2 + b); hrb[o + 3 * HID] = (f16)(ar3 + b);
}

// ================= pure gather (fp16 rows, fp32 accumulate, fp16 inout) =======
// 2 nodes per wave, 4-edge unroll -> 8 independent row loads in flight.

template <bool RELU>
__global__ void gather_kernel(const f16* __restrict__ hn,
                              const int* __restrict__ rs,
                              const int* __restrict__ re,
                              const float* __restrict__ inv,
                              f16* hio) {
    int lane = threadIdx.x & 63;
    int wid = (blockIdx.x * blockDim.x + threadIdx.x) >> 6;
    int m0 = __builtin_amdgcn_readfirstlane(wid << 1);

    int e0  = __builtin_amdgcn_readfirstlane(rs[m0]);
    int re0 = __builtin_amdgcn_readfirstlane(re[m0]);
    int e1  = __builtin_amdgcn_readfirstlane(rs[m0 + 1]);
    int re1 = __builtin_amdgcn_readfirstlane(re[m0 + 1]);
    const int* col = (const int*)hio;  // unused; silence nothing
    (void)col;

    extern __shared__ int dummy[];  // (no LDS actually used)

    const int* colp = nullptr;
    (void)colp;

    float a0 = 0.f, a1 = 0.f;
    // col array passed via global pointer below
    // (see launch: col bound as separate arg)
    // -- placeholder removed; real col arg:
    // (kept signature minimal: col passed as 6th arg)
    // NOTE: actual implementation below uses 'colg'
    a0 = a0; a1 = a1;
    // real body in gather2_kernel
    (void)e0; (void)re0; (void)e1; (void)re1; (void)hn; (void)inv; (void)hio;
    (void)lane; (void)m0;
}

template <bool RELU>
__global__ void gather2_kernel(const f16* __restrict__ hn,
                               const int* __restrict__ rs,
                               const int* __restrict__ re,
                               const int* __restrict__ col,
                               const float* __restrict__ inv,
                               f16* hio) {
    int lane = threadIdx.x & 63;
    int wid = (blockIdx.x * blockDim.x + threadIdx.x) >> 6;
    int m0 = __builtin_amdgcn_readfirstlane(wid << 1);

    int e0  = __builtin_amdgcn_readfirstlane(rs[m0]);
    int re0 = __builtin_amdgcn_readfirstlane(re[m0]);
    int e1  = __builtin_amdgcn_readfirstlane(rs[m0 + 1]);
    int re1 = __builtin_amdgcn_readfirstlane(re[m0 + 1]);

    float a0 = 0.f, a1 = 0.f;

    while (e0 + 4 <= re0 && e1 + 4 <= re1) {
        int c00 = col[e0], c01 = col[e0 + 1], c02 = col[e0 + 2], c03 = col[e0 + 3];
        int c10 = col[e1], c11 = col[e1 + 1], c12 = col[e1 + 2], c13 = col[e1 + 3];
        float v00 = (float)hn[(size_t)c00 * HID + lane];
        float v01 = (float)hn[(size_t)c01 * HID + lane];
        float v02 = (float)hn[(size_t)c02 * HID + lane];
        float v03 = (float)hn[(size_t)c03 * HID + lane];
        float v10 = (float)hn[(size_t)c10 * HID + lane];
        float v11 = (float)hn[(size_t)c11 * HID + lane];
        float v12 = (float)hn[(size_t)c12 * HID + lane];
        float v13 = (float)hn[(size_t)c13 * HID + lane];
        a0 += (v00 + v01) + (v02 + v03);
        a1 += (v10 + v11) + (v12 + v13);
        e0 += 4; e1 += 4;
    }
    while (e0 + 4 <= re0) {
        int c0 = col[e0], c1 = col[e0 + 1], c2 = col[e0 + 2], c3 = col[e0 + 3];
        a0 += ((float)hn[(size_t)c0 * HID + lane] + (float)hn[(size_t)c1 * HID + lane]) +
              ((float)hn[(size_t)c2 * HID + lane] + (float)hn[(size_t)c3 * HID + lane]);
        e0 += 4;
    }
    while (e1 + 4 <= re1) {
        int c0 = col[e1], c1 = col[e1 + 1], c2 = col[e1 + 2], c3 = col[e1 + 3];
        a1 += ((float)hn[(size_t)c0 * HID + lane] + (float)hn[(size_t)c1 * HID + lane]) +
              ((float)hn[(size_t)c2 * HID + lane] + (float)hn[(size_t)c3 * HID + lane]);
        e1 += 4;
    }
    while (e0 < re0) { a0 += (float)hn[(size_t)col[e0] * HID + lane]; ++e0; }
    while (e1 < re1) { a1 += (float)hn[(size_t)col[e1] * HID + lane]; ++e1; }

    size_t o = (size_t)m0 * HID + lane;
    float r0 = fmaf(a0, inv[m0], (float)hio[o]);
    float r1 = fmaf(a1, inv[m0 + 1], (float)hio[o + HID]);
    if (RELU) { r0 = fmaxf(r0, 0.f); r1 = fmaxf(r1, 0.f); }
    hio[o] = (f16)r0;
    hio[o + HID] = (f16)r1;
}

// ================= fused predictor head (fp16 input) =================

__global__ void head_kernel(const f16* __restrict__ h,
                            const float* __restrict__ Wp1,
                            const float* __restrict__ bp1,
                            const float* __restrict__ Wp2,
                            const float* __restrict__ bp2,
                            float* __restrict__ out) {
    int lane = threadIdx.x & 63;
    int wid = (blockIdx.x * blockDim.x + threadIdx.x) >> 6;
    int m0 = __builtin_amdgcn_readfirstlane(wid << 2);
    const unsigned* h0 = (const unsigned*)h + (size_t)m0 * 32;

    float a0 = 0.f, a1 = 0.f, a2 = 0.f, a3 = 0.f;
#pragma unroll
    for (int kk = 0; kk < 32; ++kk) {
        f16x2 p0 = u2h(h0[kk]);
        f16x2 p1 = u2h(h0[32 + kk]);
        f16x2 p2 = u2h(h0[64 + kk]);
        f16x2 p3 = u2h(h0[96 + kk]);
        int k = kk << 1;
        float wA = Wp1[k * HID + lane];
        float wB = Wp1[(k + 1) * HID + lane];
        a0 = fmaf((float)p0.x, wA, a0); a0 = fmaf((float)p0.y, wB, a0);
        a1 = fmaf((float)p1.x, wA, a1); a1 = fmaf((float)p1.y, wB, a1);
        a2 = fmaf((float)p2.x, wA, a2); a2 = fmaf((float)p2.y, wB, a2);
        a3 = fmaf((float)p3.x, wA, a3); a3 = fmaf((float)p3.y, wB, a3);
    }
    float b = bp1[lane], w2 = Wp2[lane];
    float r0 = fmaxf(a0 + b, 0.f) * w2;
    float r1 = fmaxf(a1 + b, 0.f) * w2;
    float r2 = fmaxf(a2 + b, 0.f) * w2;
    float r3 = fmaxf(a3 + b, 0.f) * w2;
#pragma unroll
    for (int off = 32; off > 0; off >>= 1) {
        r0 += __shfl_xor(r0, off);
        r1 += __shfl_xor(r1, off);
        r2 += __shfl_xor(r2, off);
        r3 += __shfl_xor(r3, off);
    }
    if (lane == 0) {
        float bb = bp2[0];
        out[m0]     = 1.f / (1.f + expf(-(r0 + bb)));
        out[m0 + 1] = 1.f / (1.f + expf(-(r1 + bb)));
        out[m0 + 2] = 1.f / (1.f + expf(-(r2 + bb)));
        out[m0 + 3] = 1.f / (1.f + expf(-(r3 + bb)));
    }
}

extern "C" void kernel_launch(void* const* d_in, const int* in_sizes, int n_in,
                              void* d_out, int out_size, void* d_ws, size_t ws_size,
                              hipStream_t stream) {
    const float* x   = (const float*)d_in[0];
    const int* eidx  = (const int*)d_in[1];
    const float* Wn0 = (const float*)d_in[2];
    const float* bn0 = (const float*)d_in[3];
    const float* Wr0 = (const float*)d_in[4];
    const float* Wn1 = (const float*)d_in[5];
    const float* bn1 = (const float*)d_in[6];
    const float* Wr1 = (const float*)d_in[7];
    const float* Wn2 = (const float*)d_in[8];
    const float* bn2 = (const float*)d_in[9];
    const float* Wr2 = (const float*)d_in[10];
    const float* Wp1 = (const float*)d_in[11];
    const float* bp1 = (const float*)d_in[12];
    const float* Wp2 = (const float*)d_in[13];
    const float* bp2 = (const float*)d_in[14];
    float* out = (float*)d_out;

    const int* src = eidx;
    const int* dst = eidx + EE;

    char* w = (char*)d_ws;
    size_t off = 0;
    auto carve = [&](size_t bytes) -> void* {
        void* p = w + off;
        off = (off + bytes + 255) & ~(size_t)255;
        return p;
    };
    int*   rsA    = (int*)carve((size_t)NN * 4);
    int*   reA    = (int*)carve((size_t)NN * 4);
    float* inv    = (float*)carve((size_t)NN * 4);
    int*   col    = (int*)carve((size_t)BKT * SLAB * 4);   // slab layout
    int*   bfill  = (int*)carve((size_t)BKT * 4);
    f16*   A      = (f16*)carve((size_t)NN * HID * 2);     // hn fp16
    f16*   C      = (f16*)carve((size_t)NN * HID * 2);     // h/hrb fp16 (in place)
    unsigned* pairs = (unsigned*)carve((size_t)BKT * SLAB * 4);
    (void)ws_size;

    hipMemsetAsync(bfill, 0, (size_t)BKT * 4, stream);

    // CSR build: slabbed bucket sort (2 kernels)
    place_kernel<<<NWG, 256, 0, stream>>>(src, dst, bfill, pairs);
    build_kernel<<<BKT, 256, 0, stream>>>(pairs, bfill, rsA, reA, inv, col);

    const int tb = NN / 16;       // 6250 blocks: 4 waves x 4 nodes
    const int gb = NN / 8;        // 12500 blocks: 4 waves x 2 nodes

    // layer 0
    transform32_kernel<<<tb, 256, 0, stream>>>(x, Wn0, bn0, Wr0, A, C);
    gather2_kernel<true><<<gb, 256, 0, stream>>>(A, rsA, reA, col, inv, C);
    // layer 1
    transform64_kernel<<<tb, 256, 0, stream>>>(C, Wn1, bn1, Wr1, A, C);
    gather2_kernel<true><<<gb, 256, 0, stream>>>(A, rsA, reA, col, inv, C);
    // layer 2
    transform64_kernel<<<tb, 256, 0, stream>>>(C, Wn2, bn2, Wr2, A, C);
    gather2_kernel<false><<<gb, 256, 0, stream>>>(A, rsA, reA, col, inv, C);

    // fused predictor head
    head_kernel<<<tb, 256, 0, stream>>>(C, Wp1, bp1, Wp2, bp2, out);
}